// Round 11
// baseline (1112.719 us; speedup 1.0000x reference)
//
#include <hip/hip_runtime.h>
#include <hip/hip_bf16.h>
#include <math.h>

// ---- problem constants ----
#define HIDN 7168
#define NHEAD 128
#define QLRANK 1536
#define KVLRANK 512
#define QKD 128
#define VHD 128
#define RHD 64
#define SEQ 1024
#define RMS_EPS 1.1920929e-07f

typedef unsigned short u16;
typedef __attribute__((ext_vector_type(8))) short bf16x8;
typedef __attribute__((ext_vector_type(4))) float f32x4;
typedef __attribute__((ext_vector_type(8))) unsigned short u16x8;

__device__ __forceinline__ u16 f2bf(float f) {
    unsigned int u = __float_as_uint(f);
    unsigned int r = (u + 0x7FFFu + ((u >> 16) & 1u)) >> 16;
    return (u16)r;
}
__device__ __forceinline__ float bf2f(u16 v) {
    return __uint_as_float(((unsigned int)v) << 16);
}

// async global->LDS, 16B per lane. LDS dest is wave-uniform base + lane*16.
__device__ __forceinline__ void gld_lds16(const u16* g, u16* l) {
    __builtin_amdgcn_global_load_lds(
        (const __attribute__((address_space(1))) unsigned int*)g,
        (__attribute__((address_space(3))) unsigned int*)l,
        16, 0, 0);
}

// ---------------- fp32 -> bf16 conversion (x8 vectorized) ----------------
__global__ __launch_bounds__(256) void f32_to_bf16(const float* __restrict__ in,
                                                   u16* __restrict__ out, long n) {
    long i = ((long)blockIdx.x * blockDim.x + threadIdx.x) * 8;
    long stride = (long)gridDim.x * blockDim.x * 8;
    for (; i < n; i += stride) {
        float4 a = *(const float4*)(in + i);
        float4 b = *(const float4*)(in + i + 4);
        u16x8 o;
        o[0] = f2bf(a.x); o[1] = f2bf(a.y); o[2] = f2bf(a.z); o[3] = f2bf(a.w);
        o[4] = f2bf(b.x); o[5] = f2bf(b.y); o[6] = f2bf(b.z); o[7] = f2bf(b.w);
        *(u16x8*)(out + i) = o;
    }
}

// ---------------- BIG GEMM (T3+T4): C[m][n] = sum_k A[m][k]*B[n][k] ----------------
// BM=256 x BN=128 tile, BK=64, 8 waves (wave grid 4M x 2N, 64x64 out/wave,
// 32 MFMA/wave/K-tile). 3-buffer LDS ring (144 KiB -> 1 WG/CU, 2 waves/SIMD,
// the m201 regime). Counted vmcnt(6): per-wave 6 loads/K-tile; tile t+1's
// loads stay in flight across tile t's compute -> 2 compute phases of latency
// cover. ONE barrier per K-tile. Ring safety: barrier at top of iter t means
// all waves finished reading tile t-1, so stage(t+2) -> buf (t+2)%3 = (t-1)%3
// is race-free; in-flight writes during compute(t) target bufs != t%3.
// Staging map: coalesced row-grouped source (8 lanes/row) + XOR chunk swizzle
// shared by reads (0 bank conflicts, proven r3-r10). N must be %128.
template <int OUT_BF16>
__global__ __launch_bounds__(512) void gemm_big(const u16* __restrict__ A,
                                                const u16* __restrict__ B,
                                                void* __restrict__ Cv,
                                                int M, int N, int K, long ldk) {
    __shared__ u16 As[3][256 * 64];   // 3 x 32 KiB
    __shared__ u16 Bs[3][128 * 64];   // 3 x 16 KiB
    const int tid = threadIdx.x;
    const int lane = tid & 63;
    const int w = tid >> 6;            // 0..7
    const int wr = w >> 1, wc = w & 1; // wave grid 4M x 2N
    const int l15 = lane & 15, lg = lane >> 4;
    const int n0 = blockIdx.x * 128;
    const int m0 = blockIdx.y * 256;

    // staging: A 4 issues/wave (256 rows), B 2 issues/wave (128 rows);
    // each issue = 8 rows x 64 cols (8 lanes cover one 128B row).
    const int gc = (lane & 7) ^ (lane >> 3);   // XOR chunk swizzle (row&7 = lane>>3)
    const u16* asrc[4];
    const u16* bsrc[2];
    int aoff[4], boff[2];
#pragma unroll
    for (int i = 0; i < 4; ++i) {
        int R = (w * 4 + i) * 8;
        asrc[i] = A + (long)(m0 + R + (lane >> 3)) * ldk + gc * 8;
        aoff[i] = R * 64;
    }
#pragma unroll
    for (int i = 0; i < 2; ++i) {
        int R = (w * 2 + i) * 8;
        bsrc[i] = B + (long)(n0 + R + (lane >> 3)) * ldk + gc * 8;
        boff[i] = R * 64;
    }

    f32x4 acc[4][4];
    const f32x4 z = {0.f, 0.f, 0.f, 0.f};
#pragma unroll
    for (int i = 0; i < 4; ++i)
#pragma unroll
        for (int j = 0; j < 4; ++j) acc[i][j] = z;

    auto stage = [&](int t) {
        const int b3 = t % 3;
        const long ko = (long)t * 64;
#pragma unroll
        for (int i = 0; i < 4; ++i) gld_lds16(asrc[i] + ko, &As[b3][aoff[i]]);
#pragma unroll
        for (int i = 0; i < 2; ++i) gld_lds16(bsrc[i] + ko, &Bs[b3][boff[i]]);
    };

    const int T = K >> 6;
    stage(0);
    stage(1);

    for (int t = 0; t < T; ++t) {
        if (t + 1 < T) asm volatile("s_waitcnt vmcnt(6)" ::: "memory");
        else           asm volatile("s_waitcnt vmcnt(0)" ::: "memory");
        __builtin_amdgcn_s_barrier();
        __builtin_amdgcn_sched_barrier(0);
        if (t + 2 < T) stage(t + 2);
        const u16* Ab = As[t % 3];
        const u16* Bb = Bs[t % 3];
#pragma unroll
        for (int kk = 0; kk < 2; ++kk) {
            bf16x8 a[4], b[4];
#pragma unroll
            for (int i = 0; i < 4; ++i) {
                int row = wr * 64 + i * 16 + l15;
                a[i] = *(const bf16x8*)&Ab[row * 64 + ((kk * 4 + lg) ^ (row & 7)) * 8];
            }
#pragma unroll
            for (int j = 0; j < 4; ++j) {
                int row = wc * 64 + j * 16 + l15;
                b[j] = *(const bf16x8*)&Bb[row * 64 + ((kk * 4 + lg) ^ (row & 7)) * 8];
            }
            __builtin_amdgcn_s_setprio(1);
#pragma unroll
            for (int i = 0; i < 4; ++i)
#pragma unroll
                for (int j = 0; j < 4; ++j)
                    acc[i][j] = __builtin_amdgcn_mfma_f32_16x16x32_bf16(a[i], b[j], acc[i][j], 0, 0, 0);
            __builtin_amdgcn_s_setprio(0);
        }
    }

#pragma unroll
    for (int i = 0; i < 4; ++i)
#pragma unroll
        for (int j = 0; j < 4; ++j)
#pragma unroll
            for (int r = 0; r < 4; ++r) {
                int m = m0 + wr * 64 + i * 16 + lg * 4 + r;
                int n = n0 + wc * 64 + j * 16 + l15;
                if (OUT_BF16)
                    ((u16*)Cv)[(long)m * N + n] = f2bf(acc[i][j][r]);
                else
                    ((float*)Cv)[(long)m * N + n] = acc[i][j][r];
            }
}

// ---------------- small GEMM (r10 2-phase dbuf, split-K) ----------------
// 128x128 tile, BK=64, 8 waves, LDS 64 KiB dbuf -> 2 blocks/CU (4 waves/SIMD).
// Used for c_q / kv_down (small N, split-K partials).
template <int OUT_BF16>
__global__ __launch_bounds__(512) void gemm_bt(const u16* __restrict__ A,
                                               const u16* __restrict__ B,
                                               void* __restrict__ Cv,
                                               int M, int N, int Kslice, long ldk) {
    __shared__ u16 As[2 * 128 * 64];
    __shared__ u16 Bs[2 * 128 * 64];
    const int tid = threadIdx.x;
    const int lane = tid & 63;
    const int w = tid >> 6;
    const int wr = w >> 2, wc = w & 3;
    const int l15 = lane & 15, lg = lane >> 4;
    const int n0 = blockIdx.x * 128;
    const int m0 = blockIdx.y * 128;
    const long kbase = (long)blockIdx.z * Kslice;

    const u16* asrc[2];
    const u16* bsrc[2];
    int aoff[2];
#pragma unroll
    for (int i = 0; i < 2; ++i) {
        int r = (w * 2 + i) * 8 + (lane >> 3);
        int gc = (lane & 7) ^ (r & 7);
        asrc[i] = A + (long)(m0 + r) * ldk + kbase + gc * 8;
        int br = n0 + r; if (br >= N) br = N - 1;
        bsrc[i] = B + (long)br * ldk + kbase + gc * 8;
        aoff[i] = (w * 2 + i) * 512;
    }

    f32x4 acc[4][2];
    const f32x4 z = {0.f, 0.f, 0.f, 0.f};
#pragma unroll
    for (int i = 0; i < 4; ++i)
#pragma unroll
        for (int j = 0; j < 2; ++j) acc[i][j] = z;

    auto stage = [&](int bufi, int kofs) {
#pragma unroll
        for (int i = 0; i < 2; ++i) {
            gld_lds16(asrc[i] + kofs, As + bufi * 8192 + aoff[i]);
            gld_lds16(bsrc[i] + kofs, Bs + bufi * 8192 + aoff[i]);
        }
    };

    const int nsteps = Kslice >> 6;
    stage(0, 0);
    asm volatile("s_waitcnt vmcnt(0)" ::: "memory");
    __builtin_amdgcn_s_barrier();

    int cur = 0;
    for (int t = 0; t < nsteps; ++t) {
        if (t + 1 < nsteps) stage(cur ^ 1, (t + 1) * 64);
        const u16* Ab = As + cur * 8192;
        const u16* Bb = Bs + cur * 8192;
#pragma unroll
        for (int kk = 0; kk < 2; ++kk) {
            bf16x8 a[4], b[2];
#pragma unroll
            for (int i = 0; i < 4; ++i) {
                int row = wr * 64 + i * 16 + l15;
                a[i] = *(const bf16x8*)&Ab[row * 64 + ((kk * 4 + lg) ^ (row & 7)) * 8];
            }
#pragma unroll
            for (int j = 0; j < 2; ++j) {
                int row = wc * 32 + j * 16 + l15;
                b[j] = *(const bf16x8*)&Bb[row * 64 + ((kk * 4 + lg) ^ (row & 7)) * 8];
            }
#pragma unroll
            for (int i = 0; i < 4; ++i)
#pragma unroll
                for (int j = 0; j < 2; ++j)
                    acc[i][j] = __builtin_amdgcn_mfma_f32_16x16x32_bf16(a[i], b[j], acc[i][j], 0, 0, 0);
        }
        asm volatile("s_waitcnt vmcnt(0)" ::: "memory");
        __builtin_amdgcn_s_barrier();
        cur ^= 1;
    }

#pragma unroll
    for (int i = 0; i < 4; ++i)
#pragma unroll
        for (int j = 0; j < 2; ++j)
#pragma unroll
            for (int r = 0; r < 4; ++r) {
                int m = m0 + wr * 64 + i * 16 + lg * 4 + r;
                int n = n0 + wc * 32 + j * 16 + l15;
                if (n < N) {
                    if (OUT_BF16)
                        ((u16*)Cv)[(long)m * N + n] = f2bf(acc[i][j][r]);
                    else
                        ((float*)Cv)[(long)blockIdx.z * M * N + (long)m * N + n] = acc[i][j][r];
                }
            }
}

// ---------------- sum split-K partials (fp32), x4 vectorized ----------------
__global__ __launch_bounds__(256) void reduce_parts(const float* __restrict__ parts,
                                                    float* __restrict__ out,
                                                    int nparts, long mn) {
    long i = ((long)blockIdx.x * 256 + threadIdx.x) * 4;
    long stride = (long)gridDim.x * 256 * 4;
    for (; i < mn; i += stride) {
        float4 s = *(const float4*)(parts + i);
        for (int p = 1; p < nparts; ++p) {
            float4 v = *(const float4*)(parts + (long)p * mn + i);
            s.x += v.x; s.y += v.y; s.z += v.z; s.w += v.w;
        }
        *(float4*)(out + i) = s;
    }
}

// ---------------- RMSNorm (row-wise): y = x * rsqrt(mean(x^2)+eps) * w ----------------
__global__ __launch_bounds__(256) void rmsnorm_kernel(const float* __restrict__ x,
                                                      const float* __restrict__ w,
                                                      u16* __restrict__ y,
                                                      int stride, int norm_len) {
    const int row = blockIdx.x;
    const float* xr = x + (long)row * stride;
    float ss = 0.f;
    for (int i = threadIdx.x; i < norm_len; i += 256) {
        float v = xr[i];
        ss += v * v;
    }
#pragma unroll
    for (int off = 32; off > 0; off >>= 1) ss += __shfl_down(ss, off);
    __shared__ float partial[4];
    if ((threadIdx.x & 63) == 0) partial[threadIdx.x >> 6] = ss;
    __syncthreads();
    float tot = partial[0] + partial[1] + partial[2] + partial[3];
    float rs = 1.0f / sqrtf(tot / (float)norm_len + RMS_EPS);
    u16* yr = y + (long)row * norm_len;
    for (int i = threadIdx.x; i < norm_len; i += 256) yr[i] = f2bf(xr[i] * rs * w[i]);
}

// ---------------- RoPE tables (fp32): cos/sin[s][i], i<32 ----------------
__global__ void rope_tables(float* __restrict__ cos_t, float* __restrict__ sin_t) {
    int s = blockIdx.x;
    int i = threadIdx.x;  // 32 threads
    float invf = powf(10000.0f, -((float)(2 * i) / 64.0f));
    float ang = (float)s * invf;
    cos_t[s * 32 + i] = cosf(ang);
    sin_t[s * 32 + i] = sinf(ang);
}

// ---------------- RoPE on q_r, in-place on q_cr (bf16) ----------------
__global__ void rope_q(u16* __restrict__ q_cr, const float* __restrict__ cos_t,
                       const float* __restrict__ sin_t) {
    int s = blockIdx.x;
    int h = blockIdx.y * 2 + (threadIdx.x >> 5);
    int i = threadIdx.x & 31;
    u16* base = q_cr + (s * (NHEAD * 192) + h * 192 + QKD);
    float x1 = bf2f(base[i]);
    float x2 = bf2f(base[i + 32]);
    float c = cos_t[s * 32 + i], sn = sin_t[s * 32 + i];
    base[i]      = f2bf(x1 * c - x2 * sn);
    base[i + 32] = f2bf(x2 * c + x1 * sn);
}

// ---------------- RoPE on k_r (from fp32 ckv_kr cols 512..576) -> bf16 kr ----------------
__global__ void rope_k(const float* __restrict__ ckv_kr, const float* __restrict__ cos_t,
                       const float* __restrict__ sin_t, u16* __restrict__ kr) {
    int s = blockIdx.x;
    int i = threadIdx.x;  // 64 threads; first 32 active
    if (i < 32) {
        const float* base = ckv_kr + (s * 576 + 512);
        float x1 = base[i], x2 = base[i + 32];
        float c = cos_t[s * 32 + i], sn = sin_t[s * 32 + i];
        kr[s * 64 + i]      = f2bf(x1 * c - x2 * sn);
        kr[s * 64 + i + 32] = f2bf(x2 * c + x1 * sn);
    }
}

// ---------------- build vT[h][dv][s] from kv[s][h*256+128+dv] ----------------
__global__ __launch_bounds__(256) void build_vt(const u16* __restrict__ kv,
                                                u16* __restrict__ vT) {
    __shared__ u16 vtile[64][136];  // 272B row stride (16B aligned)
    const int h = blockIdx.x, sb = blockIdx.y, s0 = sb * 64;
    const int tid = threadIdx.x;
#pragma unroll
    for (int it = 0; it < 4; ++it) {
        int c = it * 256 + tid;
        int row = c >> 4;
        int off8 = (c & 15) * 8;
        *(u16x8*)&vtile[row][off8] =
            *(const u16x8*)&kv[(s0 + row) * 32768 + h * 256 + 128 + off8];
    }
    __syncthreads();
    const int sl = tid & 63;
    const int dvb = tid >> 6;  // 0..3
#pragma unroll
    for (int it = 0; it < 32; ++it) {
        int dv = dvb + it * 4;
        vT[(h * 128 + dv) * 1024 + s0 + sl] = vtile[sl][dv];
    }
}

// ---------------- flash attention: 1 block = 128 queries x 1 head, 8 waves ----------------
// T14 async-STAGE (reg prefetch of next tile under compute) + T5 setprio
// around MFMA clusters. p_lds is wave-private -> no barrier after P-write.
__global__ __launch_bounds__(512) void mla_attn(const u16* __restrict__ q_cr,
                                                const u16* __restrict__ kv,
                                                const u16* __restrict__ kr,
                                                const u16* __restrict__ vT,
                                                u16* __restrict__ o_g) {
    __shared__ u16 ks[64][200];        // 64 keys x 192 dims (+pad)
    __shared__ u16 vts[128][72];       // 128 dv x 64 k (+pad)
    __shared__ u16 p_lds[8][16][72];   // per wave: 16 q x 64 k (+pad)
    const int qb = blockIdx.x, h = blockIdx.y;
    const int s0q = qb * 128;
    const int tid = threadIdx.x, lane = tid & 63, w = tid >> 6;
    const int l15 = lane & 15, lg = lane >> 4;
    const float scale = 0.07216878364870323f;  // 1/sqrt(192)

    // Q in registers, A-fragment layout (row = l15, k contiguous per lg group)
    bf16x8 qreg[6];
    {
        const int qrow = s0q + w * 16 + l15;
#pragma unroll
        for (int kk = 0; kk < 6; ++kk)
            qreg[kk] = *(const bf16x8*)&q_cr[qrow * (NHEAD * 192) + h * 192 + kk * 32 + lg * 8];
    }

    // staging-index precompute (512 threads cover: K 2x, kr 1x, V 2x u16x8 each)
    const int krow0 = tid >> 4,           koff0 = (tid & 15) * 8;
    const int krow1 = (512 + tid) >> 4,   koff1 = ((512 + tid) & 15) * 8;
    const int rrow  = tid >> 3,           roff  = (tid & 7) * 8;
    const int vdv0  = tid >> 3,           voff0 = (tid & 7) * 8;
    const int vdv1  = (512 + tid) >> 3,   voff1 = ((512 + tid) & 7) * 8;
    const u16* kvp = kv + h * 256;
    const u16* vtp = vT + (long)(h * 128) * 1024;

    u16x8 kreg0, kreg1, krreg, vreg0, vreg1;
    auto load_tile = [&](int s0k) {
        kreg0 = *(const u16x8*)&kvp[(long)(s0k + krow0) * 32768 + koff0];
        kreg1 = *(const u16x8*)&kvp[(long)(s0k + krow1) * 32768 + koff1];
        krreg = *(const u16x8*)&kr[(s0k + rrow) * 64 + roff];
        vreg0 = *(const u16x8*)&vtp[(long)vdv0 * 1024 + s0k + voff0];
        vreg1 = *(const u16x8*)&vtp[(long)vdv1 * 1024 + s0k + voff1];
    };

    f32x4 o_acc[8];
    const f32x4 z = {0.f, 0.f, 0.f, 0.f};
#pragma unroll
    for (int d = 0; d < 8; ++d) o_acc[d] = z;
    float m_r[4], l_r[4];
#pragma unroll
    for (int r = 0; r < 4; ++r) { m_r[r] = -1e30f; l_r[r] = 0.f; }

    load_tile(0);

    for (int kt = 0; kt < 16; ++kt) {
        __syncthreads();   // prev tile's readers done
        *(u16x8*)&ks[krow0][koff0]      = kreg0;
        *(u16x8*)&ks[krow1][koff1]      = kreg1;
        *(u16x8*)&ks[rrow][128 + roff]  = krreg;
        *(u16x8*)&vts[vdv0][voff0]      = vreg0;
        *(u16x8*)&vts[vdv1][voff1]      = vreg1;
        __syncthreads();   // tile staged
        if (kt + 1 < 16) load_tile((kt + 1) * 64);   // async: hides under compute

        // QK^T : S-frags (16 q x 64 keys per wave)
        f32x4 sf[4];
#pragma unroll
        for (int j = 0; j < 4; ++j) sf[j] = z;
        __builtin_amdgcn_s_setprio(1);
#pragma unroll
        for (int kk = 0; kk < 6; ++kk) {
            bf16x8 a = qreg[kk];
#pragma unroll
            for (int j = 0; j < 4; ++j) {
                bf16x8 b = *(const bf16x8*)&ks[j * 16 + l15][kk * 32 + lg * 8];
                sf[j] = __builtin_amdgcn_mfma_f32_16x16x32_bf16(a, b, sf[j], 0, 0, 0);
            }
        }
        __builtin_amdgcn_s_setprio(0);

        // online softmax (rows live in C-layout: row=(lg)*4+r, col=j*16+l15)
        float p[4][4];
        float alpha[4];
#pragma unroll
        for (int r = 0; r < 4; ++r) {
            float mx = fmaxf(fmaxf(sf[0][r], sf[1][r]), fmaxf(sf[2][r], sf[3][r]));
#pragma unroll
            for (int off = 1; off < 16; off <<= 1) mx = fmaxf(mx, __shfl_xor(mx, off));
            mx *= scale;
            float mnew = fmaxf(m_r[r], mx);
            alpha[r] = __expf(m_r[r] - mnew);
            float rs = 0.f;
#pragma unroll
            for (int j = 0; j < 4; ++j) {
                float pv = __expf(sf[j][r] * scale - mnew);
                p[j][r] = pv;
                rs += pv;
            }
#pragma unroll
            for (int off = 1; off < 16; off <<= 1) rs += __shfl_xor(rs, off);
            l_r[r] = l_r[r] * alpha[r] + rs;
            m_r[r] = mnew;
        }
#pragma unroll
        for (int d = 0; d < 8; ++d)
#pragma unroll
            for (int r = 0; r < 4; ++r) o_acc[d][r] *= alpha[r];

        // P -> LDS (wave-private; no block barrier needed)
#pragma unroll
        for (int j = 0; j < 4; ++j)
#pragma unroll
            for (int r = 0; r < 4; ++r)
                p_lds[w][lg * 4 + r][j * 16 + l15] = f2bf(p[j][r]);

        // PV: O += P @ V
        __builtin_amdgcn_s_setprio(1);
#pragma unroll
        for (int kk2 = 0; kk2 < 2; ++kk2) {
            bf16x8 a = *(const bf16x8*)&p_lds[w][l15][kk2 * 32 + lg * 8];
#pragma unroll
            for (int d = 0; d < 8; ++d) {
                bf16x8 b = *(const bf16x8*)&vts[d * 16 + l15][kk2 * 32 + lg * 8];
                o_acc[d] = __builtin_amdgcn_mfma_f32_16x16x32_bf16(a, b, o_acc[d], 0, 0, 0);
            }
        }
        __builtin_amdgcn_s_setprio(0);
    }

    // epilogue: divide by l, store bf16 o[s][h*128+dv]
#pragma unroll
    for (int d = 0; d < 8; ++d)
#pragma unroll
        for (int r = 0; r < 4; ++r) {
            int srow = s0q + w * 16 + lg * 4 + r;
            float v = o_acc[d][r] / l_r[r];
            o_g[srow * 16384 + h * 128 + d * 16 + l15] = f2bf(v);
        }
}

// ---------------- host launcher ----------------
extern "C" void kernel_launch(void* const* d_in, const int* in_sizes, int n_in,
                              void* d_out, int out_size, void* d_ws, size_t ws_size,
                              hipStream_t stream) {
    const float* hs        = (const float*)d_in[0];
    const float* w_q_down  = (const float*)d_in[1];
    const float* q_norm_w  = (const float*)d_in[2];
    const float* w_q_up    = (const float*)d_in[3];
    const float* w_kv_down = (const float*)d_in[4];
    const float* kv_norm_w = (const float*)d_in[5];
    const float* w_kv_up   = (const float*)d_in[6];
    const float* w_out     = (const float*)d_in[7];
    float* out = (float*)d_out;
    char* ws = (char*)d_ws;

    // ---- workspace layout (contiguous front region is reused for w_out bf16) ----
    const size_t SZ_HS   = (size_t)SEQ * HIDN * 2;            // 14,680,064
    const size_t SZ_KV   = (size_t)SEQ * 32768 * 2;           // 67,108,864
    const size_t SZ_QCR  = (size_t)SEQ * (NHEAD * 192) * 2;   // 50,331,648
    const size_t SZ_VT   = (size_t)NHEAD * 128 * 1024 * 2;    // 33,554,432
    const size_t SZ_WB   = (size_t)24576 * 1536 * 2;          // 75,497,472 (max of small weights)
    const size_t SZ_CQ   = (size_t)SEQ * QLRANK * 4;
    const size_t SZ_CQN  = (size_t)SEQ * QLRANK * 2;
    const size_t SZ_CKV  = (size_t)SEQ * 576 * 4;
    const size_t SZ_CKVN = (size_t)SEQ * KVLRANK * 2;
    const size_t SZ_KR   = (size_t)SEQ * 64 * 2;
    const size_t SZ_OG   = (size_t)SEQ * 16384 * 2;
    const size_t SZ_TAB  = (size_t)SEQ * 32 * 4;

    size_t off = 0;
    u16* hs_bf  = (u16*)(ws + off); off += SZ_HS;
    u16* kvb    = (u16*)(ws + off); off += SZ_KV;
    u16* q_cr   = (u16*)(ws + off); off += SZ_QCR;
    u16* vT     = (u16*)(ws + off); off += SZ_VT;
    u16* W_BUF  = (u16*)(ws + off); off += SZ_WB;
    // split-K partials for c_q/kv_down alias upper W_BUF region (+32MB; weight
    // there is <32MB while these gemms run).
    float* parts = (float*)((char*)W_BUF + 33554432);
    // w_out bf16 (234,881,024 B) aliases [ws .. 235MB), all dead by then
    u16* wout_bf = (u16*)ws;
    float* c_q    = (float*)(ws + off); off += SZ_CQ;
    u16* cq_n     = (u16*)(ws + off); off += SZ_CQN;
    float* ckv_kr = (float*)(ws + off); off += SZ_CKV;
    u16* ckv_n    = (u16*)(ws + off); off += SZ_CKVN;
    u16* kr       = (u16*)(ws + off); off += SZ_KR;
    u16* o_g      = (u16*)(ws + off); off += SZ_OG;
    float* cos_t  = (float*)(ws + off); off += SZ_TAB;
    float* sin_t  = (float*)(ws + off); off += SZ_TAB;
    (void)in_sizes; (void)n_in; (void)out_size; (void)ws_size;

    rope_tables<<<dim3(SEQ), dim3(32), 0, stream>>>(cos_t, sin_t);
    f32_to_bf16<<<2048, 256, 0, stream>>>(hs, hs_bf, (long)SEQ * HIDN);

    // c_q = hs @ w_q_down^T   (split-K x4: 7168 = 4 x 1792)
    f32_to_bf16<<<2048, 256, 0, stream>>>(w_q_down, W_BUF, (long)QLRANK * HIDN);
    gemm_bt<0><<<dim3(QLRANK / 128, SEQ / 128, 4), 512, 0, stream>>>(hs_bf, W_BUF, parts, SEQ, QLRANK, HIDN / 4, HIDN);
    reduce_parts<<<1024, 256, 0, stream>>>(parts, c_q, 4, (long)SEQ * QLRANK);
    rmsnorm_kernel<<<SEQ, 256, 0, stream>>>(c_q, q_norm_w, cq_n, QLRANK, QLRANK);

    // q_cr = rmsnorm(c_q) @ w_q_up^T   (big kernel: grid 192x4)
    f32_to_bf16<<<2048, 256, 0, stream>>>(w_q_up, W_BUF, (long)24576 * QLRANK);
    gemm_big<1><<<dim3(24576 / 128, SEQ / 256), 512, 0, stream>>>(cq_n, W_BUF, q_cr, SEQ, 24576, QLRANK, QLRANK);

    // ckv_kr = hs @ w_kv_down^T   (split-K x8; N=576 ragged)
    f32_to_bf16<<<2048, 256, 0, stream>>>(w_kv_down, W_BUF, (long)576 * HIDN);
    gemm_bt<0><<<dim3(5, SEQ / 128, 8), 512, 0, stream>>>(hs_bf, W_BUF, parts, SEQ, 576, HIDN / 8, HIDN);
    reduce_parts<<<1024, 256, 0, stream>>>(parts, ckv_kr, 8, (long)SEQ * 576);
    rmsnorm_kernel<<<SEQ, 256, 0, stream>>>(ckv_kr, kv_norm_w, ckv_n, 576, KVLRANK);
    rope_k<<<SEQ, 64, 0, stream>>>(ckv_kr, cos_t, sin_t, kr);

    // kv = rmsnorm(c_kv) @ w_kv_up^T   (big kernel: grid 256x4)
    f32_to_bf16<<<2048, 256, 0, stream>>>(w_kv_up, W_BUF, (long)32768 * KVLRANK);
    gemm_big<1><<<dim3(32768 / 128, SEQ / 256), 512, 0, stream>>>(ckv_n, W_BUF, kvb, SEQ, 32768, KVLRANK, KVLRANK);

    rope_q<<<dim3(SEQ, NHEAD / 2), 64, 0, stream>>>(q_cr, cos_t, sin_t);
    build_vt<<<dim3(NHEAD, SEQ / 64), 256, 0, stream>>>(kvb, vT);

    mla_attn<<<dim3(SEQ / 128, NHEAD), 512, 0, stream>>>(q_cr, kvb, kr, vT, o_g);

    // out = o @ w_out^T   (big kernel: grid 56x4; natural order keeps B-strip
    // on one XCD's L2 since 56 % 8 == 0)
    f32_to_bf16<<<4096, 256, 0, stream>>>(w_out, wout_bf, (long)HIDN * 16384);
    gemm_big<0><<<dim3(HIDN / 128, SEQ / 256), 512, 0, stream>>>(o_g, wout_bf, out, SEQ, HIDN, 16384, 16384);
}

// Round 12
// 980.787 us; speedup vs baseline: 1.1345x; 1.1345x over previous
//
#include <hip/hip_runtime.h>
#include <hip/hip_bf16.h>
#include <math.h>

// ---- problem constants ----
#define HIDN 7168
#define NHEAD 128
#define QLRANK 1536
#define KVLRANK 512
#define QKD 128
#define VHD 128
#define RHD 64
#define SEQ 1024
#define RMS_EPS 1.1920929e-07f

typedef unsigned short u16;
typedef __attribute__((ext_vector_type(8))) short bf16x8;
typedef __attribute__((ext_vector_type(4))) float f32x4;
typedef __attribute__((ext_vector_type(4))) unsigned short u16x4;
typedef __attribute__((ext_vector_type(8))) unsigned short u16x8;

__device__ __forceinline__ u16 f2bf(float f) {
    unsigned int u = __float_as_uint(f);
    unsigned int r = (u + 0x7FFFu + ((u >> 16) & 1u)) >> 16;
    return (u16)r;
}
__device__ __forceinline__ float bf2f(u16 v) {
    return __uint_as_float(((unsigned int)v) << 16);
}

// async global->LDS, 16B per lane. LDS dest is wave-uniform base + lane*16.
__device__ __forceinline__ void gld_lds16(const u16* g, u16* l) {
    __builtin_amdgcn_global_load_lds(
        (const __attribute__((address_space(1))) unsigned int*)g,
        (__attribute__((address_space(3))) unsigned int*)l,
        16, 0, 0);
}

// ---------------- fp32 -> bf16 conversion (x8 vectorized) ----------------
__global__ __launch_bounds__(256) void f32_to_bf16(const float* __restrict__ in,
                                                   u16* __restrict__ out, long n) {
    long i = ((long)blockIdx.x * blockDim.x + threadIdx.x) * 8;
    long stride = (long)gridDim.x * blockDim.x * 8;
    for (; i < n; i += stride) {
        float4 a = *(const float4*)(in + i);
        float4 b = *(const float4*)(in + i + 4);
        u16x8 o;
        o[0] = f2bf(a.x); o[1] = f2bf(a.y); o[2] = f2bf(a.z); o[3] = f2bf(a.w);
        o[4] = f2bf(b.x); o[5] = f2bf(b.y); o[6] = f2bf(b.z); o[7] = f2bf(b.w);
        *(u16x8*)(out + i) = o;
    }
}

// ---------------- GEMM with FUSED fp32->bf16 on B ----------------
// C[m][n] = sum_k A[m][k] * B[n][k];  A bf16 (global_load_lds staging),
// B fp32 WEIGHT read directly + converted in-registers (kills the separate
// conversion pass: -750MB HBM round-trip).  r10-proven structure otherwise:
// 128x128 tile, BK=64, 8 waves (wave grid 2Mx4N, 64x32 out/wave), 64 KiB
// LDS dbuf -> 2 blocks/CU = 4 waves/SIMD TLP.  B staging is T14-style:
// issue fp32 loads with next tile's A-lds, compute current, vmcnt(0),
// convert+ds_write into the SAME XOR-swizzled layout the readers use,
// lgkmcnt(0), barrier.  Race-free: writes target buf^1 whose readers all
// passed the previous barrier.  Split-K via blockIdx.z (OUT_BF16=0 only).
template <int OUT_BF16>
__global__ __launch_bounds__(512) void gemm_bt(const u16* __restrict__ A,
                                               const float* __restrict__ B,
                                               void* __restrict__ Cv,
                                               int M, int N, int Kslice, long ldk) {
    __shared__ u16 As[2 * 128 * 64];   // 2 x 16 KiB
    __shared__ u16 Bs[2 * 128 * 64];
    const int tid = threadIdx.x;
    const int lane = tid & 63;
    const int w = tid >> 6;            // 0..7
    const int wr = w >> 2, wc = w & 3; // wave grid 2M x 4N
    const int l15 = lane & 15, lg = lane >> 4;
    const int n0 = blockIdx.x * 128;
    const int m0 = blockIdx.y * 128;
    const long kbase = (long)blockIdx.z * Kslice;

    // A staging: 2 issues/wave, each 8 rows x 64 cols; 8 lanes cover a 128B row;
    // global chunk = (lane&7) ^ (row&7)  (XOR swizzle shared with readers).
    const u16* asrc[2];
    int aoff[2];
#pragma unroll
    for (int i = 0; i < 2; ++i) {
        int r = (w * 2 + i) * 8 + (lane >> 3);
        int gc = (lane & 7) ^ (r & 7);
        asrc[i] = A + (long)(m0 + r) * ldk + kbase + gc * 8;
        aoff[i] = (w * 2 + i) * 512;
    }

    // B fp32 reg-staging: per-wave rows [w*16, w*16+16); 4 x float4 per lane.
    // chunk c = i*64+lane: row = c>>4, 16B-fp32-chunk ch = c&15 (16 per row).
    // bf16 dest: logical 16B chunk ch>>1, half ch&1; phys = (ch>>1)^(row&7).
    const float* bsrcf[4];
    int bdst[4];
#pragma unroll
    for (int i = 0; i < 4; ++i) {
        int c = i * 64 + lane;
        int rl = c >> 4, ch = c & 15;
        int lrow = w * 16 + rl;
        int gr = n0 + lrow; if (gr >= N) gr = N - 1;
        bsrcf[i] = B + (long)gr * ldk + kbase + ch * 4;
        bdst[i] = lrow * 64 + (((ch >> 1) ^ (lrow & 7)) * 8) + (ch & 1) * 4;
    }

    f32x4 acc[4][2];
    const f32x4 z = {0.f, 0.f, 0.f, 0.f};
#pragma unroll
    for (int i = 0; i < 4; ++i)
#pragma unroll
        for (int j = 0; j < 2; ++j) acc[i][j] = z;

    float4 bv[4];
    auto stageA = [&](int bufi, int kofs) {
#pragma unroll
        for (int i = 0; i < 2; ++i)
            gld_lds16(asrc[i] + kofs, As + bufi * 8192 + aoff[i]);
    };
    auto loadB = [&](int kofs) {
#pragma unroll
        for (int i = 0; i < 4; ++i) bv[i] = *(const float4*)(bsrcf[i] + kofs);
    };
    auto writeB = [&](int bufi) {
#pragma unroll
        for (int i = 0; i < 4; ++i) {
            u16x4 o;
            o[0] = f2bf(bv[i].x); o[1] = f2bf(bv[i].y);
            o[2] = f2bf(bv[i].z); o[3] = f2bf(bv[i].w);
            *(u16x4*)&Bs[bufi * 8192 + bdst[i]] = o;
        }
    };

    const int nsteps = Kslice >> 6;
    // prologue: tile 0
    stageA(0, 0);
    loadB(0);
    asm volatile("s_waitcnt vmcnt(0)" ::: "memory");
    writeB(0);
    asm volatile("s_waitcnt lgkmcnt(0)" ::: "memory");
    __builtin_amdgcn_s_barrier();

    int cur = 0;
    for (int t = 0; t < nsteps; ++t) {
        if (t + 1 < nsteps) {
            stageA(cur ^ 1, (t + 1) * 64);
            loadB((t + 1) * 64);
        }
        const u16* Ab = As + cur * 8192;
        const u16* Bb = Bs + cur * 8192;
#pragma unroll
        for (int kk = 0; kk < 2; ++kk) {
            bf16x8 a[4], b[2];
#pragma unroll
            for (int i = 0; i < 4; ++i) {
                int row = wr * 64 + i * 16 + l15;
                a[i] = *(const bf16x8*)&Ab[row * 64 + ((kk * 4 + lg) ^ (row & 7)) * 8];
            }
#pragma unroll
            for (int j = 0; j < 2; ++j) {
                int row = wc * 32 + j * 16 + l15;
                b[j] = *(const bf16x8*)&Bb[row * 64 + ((kk * 4 + lg) ^ (row & 7)) * 8];
            }
#pragma unroll
            for (int i = 0; i < 4; ++i)
#pragma unroll
                for (int j = 0; j < 2; ++j)
                    acc[i][j] = __builtin_amdgcn_mfma_f32_16x16x32_bf16(a[i], b[j], acc[i][j], 0, 0, 0);
        }
        asm volatile("s_waitcnt vmcnt(0)" ::: "memory");   // A-lds + B fp32 landed
        if (t + 1 < nsteps) writeB(cur ^ 1);
        asm volatile("s_waitcnt lgkmcnt(0)" ::: "memory"); // ds_writes visible
        __builtin_amdgcn_s_barrier();
        cur ^= 1;
    }

#pragma unroll
    for (int i = 0; i < 4; ++i)
#pragma unroll
        for (int j = 0; j < 2; ++j)
#pragma unroll
            for (int r = 0; r < 4; ++r) {
                int m = m0 + wr * 64 + i * 16 + lg * 4 + r;
                int n = n0 + wc * 32 + j * 16 + l15;
                if (n < N) {
                    if (OUT_BF16)
                        ((u16*)Cv)[(long)m * N + n] = f2bf(acc[i][j][r]);
                    else
                        ((float*)Cv)[(long)blockIdx.z * M * N + (long)m * N + n] = acc[i][j][r];
                }
            }
}

// ---------------- sum split-K partials (fp32), x4 vectorized ----------------
__global__ __launch_bounds__(256) void reduce_parts(const float* __restrict__ parts,
                                                    float* __restrict__ out,
                                                    int nparts, long mn) {
    long i = ((long)blockIdx.x * 256 + threadIdx.x) * 4;
    long stride = (long)gridDim.x * 256 * 4;
    for (; i < mn; i += stride) {
        float4 s = *(const float4*)(parts + i);
        for (int p = 1; p < nparts; ++p) {
            float4 v = *(const float4*)(parts + (long)p * mn + i);
            s.x += v.x; s.y += v.y; s.z += v.z; s.w += v.w;
        }
        *(float4*)(out + i) = s;
    }
}

// ---------------- RMSNorm (row-wise): y = x * rsqrt(mean(x^2)+eps) * w ----------------
__global__ __launch_bounds__(256) void rmsnorm_kernel(const float* __restrict__ x,
                                                      const float* __restrict__ w,
                                                      u16* __restrict__ y,
                                                      int stride, int norm_len) {
    const int row = blockIdx.x;
    const float* xr = x + (long)row * stride;
    float ss = 0.f;
    for (int i = threadIdx.x; i < norm_len; i += 256) {
        float v = xr[i];
        ss += v * v;
    }
#pragma unroll
    for (int off = 32; off > 0; off >>= 1) ss += __shfl_down(ss, off);
    __shared__ float partial[4];
    if ((threadIdx.x & 63) == 0) partial[threadIdx.x >> 6] = ss;
    __syncthreads();
    float tot = partial[0] + partial[1] + partial[2] + partial[3];
    float rs = 1.0f / sqrtf(tot / (float)norm_len + RMS_EPS);
    u16* yr = y + (long)row * norm_len;
    for (int i = threadIdx.x; i < norm_len; i += 256) yr[i] = f2bf(xr[i] * rs * w[i]);
}

// ---------------- RoPE tables (fp32): cos/sin[s][i], i<32 ----------------
__global__ void rope_tables(float* __restrict__ cos_t, float* __restrict__ sin_t) {
    int s = blockIdx.x;
    int i = threadIdx.x;  // 32 threads
    float invf = powf(10000.0f, -((float)(2 * i) / 64.0f));
    float ang = (float)s * invf;
    cos_t[s * 32 + i] = cosf(ang);
    sin_t[s * 32 + i] = sinf(ang);
}

// ---------------- RoPE on q_r, in-place on q_cr (bf16) ----------------
__global__ void rope_q(u16* __restrict__ q_cr, const float* __restrict__ cos_t,
                       const float* __restrict__ sin_t) {
    int s = blockIdx.x;
    int h = blockIdx.y * 2 + (threadIdx.x >> 5);
    int i = threadIdx.x & 31;
    u16* base = q_cr + (s * (NHEAD * 192) + h * 192 + QKD);
    float x1 = bf2f(base[i]);
    float x2 = bf2f(base[i + 32]);
    float c = cos_t[s * 32 + i], sn = sin_t[s * 32 + i];
    base[i]      = f2bf(x1 * c - x2 * sn);
    base[i + 32] = f2bf(x2 * c + x1 * sn);
}

// ---------------- RoPE on k_r (from fp32 ckv_kr cols 512..576) -> bf16 kr ----------------
__global__ void rope_k(const float* __restrict__ ckv_kr, const float* __restrict__ cos_t,
                       const float* __restrict__ sin_t, u16* __restrict__ kr) {
    int s = blockIdx.x;
    int i = threadIdx.x;  // 64 threads; first 32 active
    if (i < 32) {
        const float* base = ckv_kr + (s * 576 + 512);
        float x1 = base[i], x2 = base[i + 32];
        float c = cos_t[s * 32 + i], sn = sin_t[s * 32 + i];
        kr[s * 64 + i]      = f2bf(x1 * c - x2 * sn);
        kr[s * 64 + i + 32] = f2bf(x2 * c + x1 * sn);
    }
}

// ---------------- build vT[h][dv][s] from kv[s][h*256+128+dv] ----------------
__global__ __launch_bounds__(256) void build_vt(const u16* __restrict__ kv,
                                                u16* __restrict__ vT) {
    __shared__ u16 vtile[64][136];  // 272B row stride (16B aligned)
    const int h = blockIdx.x, sb = blockIdx.y, s0 = sb * 64;
    const int tid = threadIdx.x;
#pragma unroll
    for (int it = 0; it < 4; ++it) {
        int c = it * 256 + tid;
        int row = c >> 4;
        int off8 = (c & 15) * 8;
        *(u16x8*)&vtile[row][off8] =
            *(const u16x8*)&kv[(s0 + row) * 32768 + h * 256 + 128 + off8];
    }
    __syncthreads();
    const int sl = tid & 63;
    const int dvb = tid >> 6;  // 0..3
#pragma unroll
    for (int it = 0; it < 32; ++it) {
        int dv = dvb + it * 4;
        vT[(h * 128 + dv) * 1024 + s0 + sl] = vtile[sl][dv];
    }
}

// ---------------- flash attention: 1 block = 128 queries x 1 head, 8 waves ----------------
// T14 async-STAGE (reg prefetch of next tile under compute) + T5 setprio
// around MFMA clusters. p_lds is wave-private -> no barrier after P-write.
__global__ __launch_bounds__(512) void mla_attn(const u16* __restrict__ q_cr,
                                                const u16* __restrict__ kv,
                                                const u16* __restrict__ kr,
                                                const u16* __restrict__ vT,
                                                u16* __restrict__ o_g) {
    __shared__ u16 ks[64][200];        // 64 keys x 192 dims (+pad)
    __shared__ u16 vts[128][72];       // 128 dv x 64 k (+pad)
    __shared__ u16 p_lds[8][16][72];   // per wave: 16 q x 64 k (+pad)
    const int qb = blockIdx.x, h = blockIdx.y;
    const int s0q = qb * 128;
    const int tid = threadIdx.x, lane = tid & 63, w = tid >> 6;
    const int l15 = lane & 15, lg = lane >> 4;
    const float scale = 0.07216878364870323f;  // 1/sqrt(192)

    // Q in registers, A-fragment layout (row = l15, k contiguous per lg group)
    bf16x8 qreg[6];
    {
        const int qrow = s0q + w * 16 + l15;
#pragma unroll
        for (int kk = 0; kk < 6; ++kk)
            qreg[kk] = *(const bf16x8*)&q_cr[qrow * (NHEAD * 192) + h * 192 + kk * 32 + lg * 8];
    }

    // staging-index precompute (512 threads cover: K 2x, kr 1x, V 2x u16x8 each)
    const int krow0 = tid >> 4,           koff0 = (tid & 15) * 8;
    const int krow1 = (512 + tid) >> 4,   koff1 = ((512 + tid) & 15) * 8;
    const int rrow  = tid >> 3,           roff  = (tid & 7) * 8;
    const int vdv0  = tid >> 3,           voff0 = (tid & 7) * 8;
    const int vdv1  = (512 + tid) >> 3,   voff1 = ((512 + tid) & 7) * 8;
    const u16* kvp = kv + h * 256;
    const u16* vtp = vT + (long)(h * 128) * 1024;

    u16x8 kreg0, kreg1, krreg, vreg0, vreg1;
    auto load_tile = [&](int s0k) {
        kreg0 = *(const u16x8*)&kvp[(long)(s0k + krow0) * 32768 + koff0];
        kreg1 = *(const u16x8*)&kvp[(long)(s0k + krow1) * 32768 + koff1];
        krreg = *(const u16x8*)&kr[(s0k + rrow) * 64 + roff];
        vreg0 = *(const u16x8*)&vtp[(long)vdv0 * 1024 + s0k + voff0];
        vreg1 = *(const u16x8*)&vtp[(long)vdv1 * 1024 + s0k + voff1];
    };

    f32x4 o_acc[8];
    const f32x4 z = {0.f, 0.f, 0.f, 0.f};
#pragma unroll
    for (int d = 0; d < 8; ++d) o_acc[d] = z;
    float m_r[4], l_r[4];
#pragma unroll
    for (int r = 0; r < 4; ++r) { m_r[r] = -1e30f; l_r[r] = 0.f; }

    load_tile(0);

    for (int kt = 0; kt < 16; ++kt) {
        __syncthreads();   // prev tile's readers done
        *(u16x8*)&ks[krow0][koff0]      = kreg0;
        *(u16x8*)&ks[krow1][koff1]      = kreg1;
        *(u16x8*)&ks[rrow][128 + roff]  = krreg;
        *(u16x8*)&vts[vdv0][voff0]      = vreg0;
        *(u16x8*)&vts[vdv1][voff1]      = vreg1;
        __syncthreads();   // tile staged
        if (kt + 1 < 16) load_tile((kt + 1) * 64);   // async: hides under compute

        // QK^T : S-frags (16 q x 64 keys per wave)
        f32x4 sf[4];
#pragma unroll
        for (int j = 0; j < 4; ++j) sf[j] = z;
        __builtin_amdgcn_s_setprio(1);
#pragma unroll
        for (int kk = 0; kk < 6; ++kk) {
            bf16x8 a = qreg[kk];
#pragma unroll
            for (int j = 0; j < 4; ++j) {
                bf16x8 b = *(const bf16x8*)&ks[j * 16 + l15][kk * 32 + lg * 8];
                sf[j] = __builtin_amdgcn_mfma_f32_16x16x32_bf16(a, b, sf[j], 0, 0, 0);
            }
        }
        __builtin_amdgcn_s_setprio(0);

        // online softmax (rows live in C-layout: row=(lg)*4+r, col=j*16+l15)
        float p[4][4];
        float alpha[4];
#pragma unroll
        for (int r = 0; r < 4; ++r) {
            float mx = fmaxf(fmaxf(sf[0][r], sf[1][r]), fmaxf(sf[2][r], sf[3][r]));
#pragma unroll
            for (int off = 1; off < 16; off <<= 1) mx = fmaxf(mx, __shfl_xor(mx, off));
            mx *= scale;
            float mnew = fmaxf(m_r[r], mx);
            alpha[r] = __expf(m_r[r] - mnew);
            float rs = 0.f;
#pragma unroll
            for (int j = 0; j < 4; ++j) {
                float pv = __expf(sf[j][r] * scale - mnew);
                p[j][r] = pv;
                rs += pv;
            }
#pragma unroll
            for (int off = 1; off < 16; off <<= 1) rs += __shfl_xor(rs, off);
            l_r[r] = l_r[r] * alpha[r] + rs;
            m_r[r] = mnew;
        }
#pragma unroll
        for (int d = 0; d < 8; ++d)
#pragma unroll
            for (int r = 0; r < 4; ++r) o_acc[d][r] *= alpha[r];

        // P -> LDS (wave-private; no block barrier needed)
#pragma unroll
        for (int j = 0; j < 4; ++j)
#pragma unroll
            for (int r = 0; r < 4; ++r)
                p_lds[w][lg * 4 + r][j * 16 + l15] = f2bf(p[j][r]);

        // PV: O += P @ V
        __builtin_amdgcn_s_setprio(1);
#pragma unroll
        for (int kk2 = 0; kk2 < 2; ++kk2) {
            bf16x8 a = *(const bf16x8*)&p_lds[w][l15][kk2 * 32 + lg * 8];
#pragma unroll
            for (int d = 0; d < 8; ++d) {
                bf16x8 b = *(const bf16x8*)&vts[d * 16 + l15][kk2 * 32 + lg * 8];
                o_acc[d] = __builtin_amdgcn_mfma_f32_16x16x32_bf16(a, b, o_acc[d], 0, 0, 0);
            }
        }
        __builtin_amdgcn_s_setprio(0);
    }

    // epilogue: divide by l, store bf16 o[s][h*128+dv]
#pragma unroll
    for (int d = 0; d < 8; ++d)
#pragma unroll
        for (int r = 0; r < 4; ++r) {
            int srow = s0q + w * 16 + lg * 4 + r;
            float v = o_acc[d][r] / l_r[r];
            o_g[srow * 16384 + h * 128 + d * 16 + l15] = f2bf(v);
        }
}

// ---------------- host launcher ----------------
extern "C" void kernel_launch(void* const* d_in, const int* in_sizes, int n_in,
                              void* d_out, int out_size, void* d_ws, size_t ws_size,
                              hipStream_t stream) {
    const float* hs        = (const float*)d_in[0];
    const float* w_q_down  = (const float*)d_in[1];
    const float* q_norm_w  = (const float*)d_in[2];
    const float* w_q_up    = (const float*)d_in[3];
    const float* w_kv_down = (const float*)d_in[4];
    const float* kv_norm_w = (const float*)d_in[5];
    const float* w_kv_up   = (const float*)d_in[6];
    const float* w_out     = (const float*)d_in[7];
    float* out = (float*)d_out;
    char* ws = (char*)d_ws;

    // ---- workspace layout (weights are no longer pre-converted) ----
    const size_t SZ_HS   = (size_t)SEQ * HIDN * 2;
    const size_t SZ_KV   = (size_t)SEQ * 32768 * 2;
    const size_t SZ_QCR  = (size_t)SEQ * (NHEAD * 192) * 2;
    const size_t SZ_VT   = (size_t)NHEAD * 128 * 1024 * 2;
    const size_t SZ_PART = (size_t)8 * SEQ * 576 > (size_t)4 * SEQ * QLRANK
                         ? (size_t)8 * SEQ * 576 * 4 : (size_t)4 * SEQ * QLRANK * 4;
    const size_t SZ_CQ   = (size_t)SEQ * QLRANK * 4;
    const size_t SZ_CQN  = (size_t)SEQ * QLRANK * 2;
    const size_t SZ_CKV  = (size_t)SEQ * 576 * 4;
    const size_t SZ_CKVN = (size_t)SEQ * KVLRANK * 2;
    const size_t SZ_KR   = (size_t)SEQ * 64 * 2;
    const size_t SZ_OG   = (size_t)SEQ * 16384 * 2;
    const size_t SZ_TAB  = (size_t)SEQ * 32 * 4;

    size_t off = 0;
    u16* hs_bf  = (u16*)(ws + off); off += SZ_HS;
    u16* kvb    = (u16*)(ws + off); off += SZ_KV;
    u16* q_cr   = (u16*)(ws + off); off += SZ_QCR;
    u16* vT     = (u16*)(ws + off); off += SZ_VT;
    float* parts = (float*)(ws + off); off += SZ_PART;
    float* c_q    = (float*)(ws + off); off += SZ_CQ;
    u16* cq_n     = (u16*)(ws + off); off += SZ_CQN;
    float* ckv_kr = (float*)(ws + off); off += SZ_CKV;
    u16* ckv_n    = (u16*)(ws + off); off += SZ_CKVN;
    u16* kr       = (u16*)(ws + off); off += SZ_KR;
    u16* o_g      = (u16*)(ws + off); off += SZ_OG;
    float* cos_t  = (float*)(ws + off); off += SZ_TAB;
    float* sin_t  = (float*)(ws + off); off += SZ_TAB;
    (void)in_sizes; (void)n_in; (void)out_size; (void)ws_size;

    rope_tables<<<dim3(SEQ), dim3(32), 0, stream>>>(cos_t, sin_t);
    f32_to_bf16<<<2048, 256, 0, stream>>>(hs, hs_bf, (long)SEQ * HIDN);

    // c_q = hs @ w_q_down^T   (split-K x4; B = fp32 weight, converted in-kernel)
    gemm_bt<0><<<dim3(QLRANK / 128, SEQ / 128, 4), 512, 0, stream>>>(hs_bf, w_q_down, parts, SEQ, QLRANK, HIDN / 4, HIDN);
    reduce_parts<<<1024, 256, 0, stream>>>(parts, c_q, 4, (long)SEQ * QLRANK);
    rmsnorm_kernel<<<SEQ, 256, 0, stream>>>(c_q, q_norm_w, cq_n, QLRANK, QLRANK);

    // q_cr = rmsnorm(c_q) @ w_q_up^T
    gemm_bt<1><<<dim3(24576 / 128, SEQ / 128), 512, 0, stream>>>(cq_n, w_q_up, q_cr, SEQ, 24576, QLRANK, QLRANK);

    // ckv_kr = hs @ w_kv_down^T   (split-K x8; N=576 ragged)
    gemm_bt<0><<<dim3(5, SEQ / 128, 8), 512, 0, stream>>>(hs_bf, w_kv_down, parts, SEQ, 576, HIDN / 8, HIDN);
    reduce_parts<<<1024, 256, 0, stream>>>(parts, ckv_kr, 8, (long)SEQ * 576);
    rmsnorm_kernel<<<SEQ, 256, 0, stream>>>(ckv_kr, kv_norm_w, ckv_n, 576, KVLRANK);
    rope_k<<<SEQ, 64, 0, stream>>>(ckv_kr, cos_t, sin_t, kr);

    // kv = rmsnorm(c_kv) @ w_kv_up^T
    gemm_bt<1><<<dim3(32768 / 128, SEQ / 128), 512, 0, stream>>>(ckv_n, w_kv_up, kvb, SEQ, 32768, KVLRANK, KVLRANK);

    rope_q<<<dim3(SEQ, NHEAD / 2), 64, 0, stream>>>(q_cr, cos_t, sin_t);
    build_vt<<<dim3(NHEAD, SEQ / 64), 256, 0, stream>>>(kvb, vT);

    mla_attn<<<dim3(SEQ / 128, NHEAD), 512, 0, stream>>>(q_cr, kvb, kr, vT, o_g);

    // out = o @ w_out^T   (B = w_out fp32 direct; no pre-conversion pass)
    gemm_bt<0><<<dim3(HIDN / 128, SEQ / 128), 512, 0, stream>>>(o_g, w_out, out, SEQ, HIDN, 16384, 16384);
}